// Round 2
// baseline (5747.617 us; speedup 1.0000x reference)
//
#include <hip/hip_runtime.h>
#include <math.h>

// Elman RNN: out[b][t][j] = H_t, H_t = tanh(X_t @ W_xh + H_{t-1} @ W_hh + b)
// Phase 1: proj_gemm writes Xp = X@W_xh + b into d_out's [B,S,H] region.
// Phase 2: ONE persistent kernel runs all 1024 steps.
//
// R6 (post-mortem of R5 regression, 4016 -> 4597 us):
//  R5's two self-inflicted wounds, now fixed:
//  (a) staging wrote 32B-contiguous per thread -> 16-way LDS bank conflict
//      (SQ_LDS_BANK_CONFLICT 0 -> 3.35e7). Now strided: thread stages qwords
//      sr+128q -> lane stride 8B, conflict-free, global still 512B/wave.
//  (b) 512 threads/block spin-polled agent-scope L3 loads untrottled
//      (~1 TB/s of poll traffic hammering the 8 hot counter lines, inflating
//      producer publish latency). Now only WAVE 1 polls (lane l checks
//      gcnt[l&31], __all, s_sleep(1) between misses) and releases the other
//      7 waves via an LDS epoch flag (zero fabric traffic).
//  R5 keepers: per-producer monotonic counter STORES (no same-address RMW),
//  2 barriers/step, 1-wave epilogue with wave-local s_waitcnt vmcnt(0) before
//  the counter publish, Xp prefetch at loop top, fast tanh.
// All cross-block H traffic stays agent-scope RELAXED atomics (complete at
// L3, coherent across XCDs). NO __threadfence (round-3 failure: full-L2
// writeback walks). W_hh strip stays asm-pinned (compiler parks it in AGPRs;
// VALU reads AGPRs directly on gfx950, so that's free).

#define B_SZ 32
#define S_SZ 1024
#define H_SZ 1024
#define K_SZ 1024

// ---------------- Phase 1: input projection GEMM (fp32) ----------------
#define BM 128
#define BN 128
#define BK 8

__global__ __launch_bounds__(256) void proj_gemm(
    const float* __restrict__ A,     // X   [M,K]
    const float* __restrict__ Bm,    // W_xh[K,N]
    const float* __restrict__ bias,  // [N]
    float* __restrict__ C,           // [M,N] (d_out Xp region)
    int M, int N, int K)
{
    __shared__ float As[BK][BM];   // transposed: As[k][m]
    __shared__ float Bs[BK][BN];

    const int tid  = threadIdx.x;
    const int row0 = blockIdx.y * BM;
    const int col0 = blockIdx.x * BN;
    const int tx = tid & 15;
    const int ty = tid >> 4;
    const int mBase = ty * 8;
    const int nBase = tx * 8;

    float acc[8][8];
    #pragma unroll
    for (int i = 0; i < 8; ++i)
        #pragma unroll
        for (int j = 0; j < 8; ++j) acc[i][j] = 0.f;

    for (int k0 = 0; k0 < K; k0 += BK) {
        {
            const int r  = tid >> 1;
            const int kq = (tid & 1) * 4;
            const float4 av = *(const float4*)(&A[(size_t)(row0 + r) * K + k0 + kq]);
            As[kq + 0][r] = av.x;
            As[kq + 1][r] = av.y;
            As[kq + 2][r] = av.z;
            As[kq + 3][r] = av.w;
            const int kr = tid >> 5;
            const int cq = (tid & 31) * 4;
            *(float4*)(&Bs[kr][cq]) =
                *(const float4*)(&Bm[(size_t)(k0 + kr) * N + col0 + cq]);
        }
        __syncthreads();

        #pragma unroll
        for (int kk = 0; kk < BK; ++kk) {
            float a[8], b[8];
            *(float4*)&a[0] = *(const float4*)&As[kk][mBase];
            *(float4*)&a[4] = *(const float4*)&As[kk][mBase + 4];
            *(float4*)&b[0] = *(const float4*)&Bs[kk][nBase];
            *(float4*)&b[4] = *(const float4*)&Bs[kk][nBase + 4];
            #pragma unroll
            for (int i = 0; i < 8; ++i)
                #pragma unroll
                for (int j = 0; j < 8; ++j)
                    acc[i][j] += a[i] * b[j];
        }
        __syncthreads();
    }

    #pragma unroll
    for (int i = 0; i < 8; ++i) {
        const int r = row0 + mBase + i;
        #pragma unroll
        for (int jq = 0; jq < 8; jq += 4) {
            const int c = col0 + nBase + jq;
            const float4 bv = *(const float4*)(&bias[c]);
            float4 o;
            o.x = acc[i][jq + 0] + bv.x;
            o.y = acc[i][jq + 1] + bv.y;
            o.z = acc[i][jq + 2] + bv.z;
            o.w = acc[i][jq + 3] + bv.w;
            *(float4*)(&C[(size_t)r * N + c]) = o;
        }
    }
}

// ---------------- init: zero the sync counters in d_ws ----------------
__global__ void init_cnt(unsigned int* __restrict__ cnt, int n) {
    int i = blockIdx.x * 256 + threadIdx.x;
    if (i < n) cnt[i] = 0u;
}

// fast tanh: tanh(x) = (e^{2x}-1)/(e^{2x}+1). Clamp keeps exp finite; output
// error ~3 ulp absolute on [-1,1] — negligible vs the 3.9e-3 absmax budget.
__device__ __forceinline__ float fast_tanh(float x) {
    const float cx = fminf(fmaxf(x, -15.f), 15.f);
    const float e  = __expf(2.f * cx);
    return __fdividef(e - 1.f, e + 1.f);
}

// ---------------- Phase 2: persistent recurrence kernel ----------------
// 256 blocks x 512 threads, 1 block/CU (grid == #CUs => co-resident).
// Block (g = blockIdx&7, c = blockIdx>>3): batches [4g,4g+4), cols [32c,+32).
// MAC partition: thread (j = tid&31 -> col, seg = tid>>5 -> K [64*seg,+64)).
// Staging partition: thread (sb = tid>>7 -> batch, sr = tid&127) stages
// qwords {sr+128q : q=0..3} of batch sb -> lane stride 8B (conflict-free),
// wave-contiguous 512B global segments.
// Sync: cnt[g][c] = #steps block (g,c) has published (monotonic store).
// Wave 1 polls all 32 counters; LDS `epoch` releases the other waves.
__global__ __launch_bounds__(512, 2) void rnn_persist(
    float* __restrict__ HS,        // d_out [B][S][H]; Xp in, H out (in place)
    const float* __restrict__ W,   // W_hh [K][H]
    float* __restrict__ Hlast,     // d_out + B*S*H
    unsigned int* __restrict__ cnt // [8][32] per-producer step counters
    )
{
    const int g    = blockIdx.x & 7;
    const int c    = blockIdx.x >> 3;
    const int col0 = c * 32;
    const int b0   = g * 4;
    const int tid  = threadIdx.x;
    const int j    = tid & 31;
    const int seg  = tid >> 5;          // 0..15

    __shared__ __align__(16) float Hs[4][1024];     // H_{t-1} for 4 batches
    __shared__ float red[8][4][32];                 // per-wave partials
    __shared__ int epoch;                           // last step seen ready

    // Load W strip into registers (once), then pin: asm makes the values
    // opaque so the compiler cannot sink/rematerialize the loads into the
    // t-loop (round-3 bug: compiler re-loaded W every step).
    float w[64];
    {
        const float* wp = W + (size_t)(seg * 64) * H_SZ + col0 + j;
        #pragma unroll
        for (int i = 0; i < 64; ++i) w[i] = wp[(size_t)i * H_SZ];
        #pragma unroll
        for (int i = 0; i < 64; ++i) asm volatile("" : "+v"(w[i]));
    }

    unsigned int* gcnt  = cnt + g * 32;
    unsigned int* mycnt = gcnt + c;

    // staging map
    const int sb = tid >> 7;            // batch 0..3
    const int sr = tid & 127;           // 128 threads per batch

    // epilogue map (wave 0 only): lanes 0..63 own (be,je) and (be+2,je)
    const int je = tid & 31;
    const int be = (tid >> 5) & 1;

    if (tid == 0) epoch = 0;
    __syncthreads();

    for (int t = 0; t < S_SZ; ++t) {
        // ---- Xp prefetch for this step (wave 0; plain loads, first touch;
        //      issued before poll/stage so latency hides under them) ----
        float xp0 = 0.f, xp1 = 0.f;
        if (tid < 64) {
            xp0 = HS[((size_t)(b0 + be)     * S_SZ + t) * H_SZ + col0 + je];
            xp1 = HS[((size_t)(b0 + be + 2) * S_SZ + t) * H_SZ + col0 + je];
        }

        if (t > 0) {
            if ((tid >> 6) == 1) {
                // ---- wave 1: poll all 32 producer counters (throttled) ----
                const unsigned int* cp = gcnt + (tid & 31); // lanes 32-63 dup
                for (;;) {
                    const unsigned int v = __hip_atomic_load(
                        cp, __ATOMIC_RELAXED, __HIP_MEMORY_SCOPE_AGENT);
                    if (__all(v >= (unsigned int)t)) break;
                    __builtin_amdgcn_s_sleep(1);
                }
                if (tid == 64)
                    __hip_atomic_store(&epoch, t, __ATOMIC_RELAXED,
                                       __HIP_MEMORY_SCOPE_WORKGROUP);
            } else {
                // ---- other waves: spin on LDS (no fabric traffic) ----
                while (__hip_atomic_load(&epoch, __ATOMIC_RELAXED,
                                         __HIP_MEMORY_SCOPE_WORKGROUP) < t) {}
            }

            // ---- stage H_{t-1} (agent atomics: L3-fresh). Strided map:
            //      lane stride 8B in LDS -> conflict-free ds_write_b64;
            //      wave covers 512B contiguous global per q. ----
            const unsigned long long* src = (const unsigned long long*)
                (&HS[((size_t)(b0 + sb) * S_SZ + (t - 1)) * H_SZ]);
            #pragma unroll
            for (int q = 0; q < 4; ++q) {
                const unsigned long long v8 = __hip_atomic_load(
                    src + sr + 128 * q, __ATOMIC_RELAXED,
                    __HIP_MEMORY_SCOPE_AGENT);
                *(unsigned long long*)(&Hs[sb][2 * (sr + 128 * q)]) = v8;
            }
            __syncthreads();   // barrier A: Hs staged

            // ---- MAC: acc[b] = sum_{k in seg range} H[b][k] * W[k][j] ----
            float acc[4];
            #pragma unroll
            for (int b = 0; b < 4; ++b) {
                const float4* hb = (const float4*)(&Hs[b][seg * 64]);
                float a = 0.f;
                #pragma unroll
                for (int q = 0; q < 16; ++q) {
                    const float4 h = hb[q];   // broadcast across 32 j-lanes
                    a += h.x * w[4 * q + 0];
                    a += h.y * w[4 * q + 1];
                    a += h.z * w[4 * q + 2];
                    a += h.w * w[4 * q + 3];
                }
                acc[b] = a;
            }
            // combine the two k-halves within the wave (seg ^ 1)
            #pragma unroll
            for (int b = 0; b < 4; ++b) acc[b] += __shfl_xor(acc[b], 32);
            const int wv = tid >> 6;
            if ((tid & 63) < 32) {
                #pragma unroll
                for (int b = 0; b < 4; ++b) red[wv][b][j] = acc[b];
            }
        }
        __syncthreads();       // barrier B: red ready (t=0: pure alignment)

        // ---- epilogue: ONE wave owns all 4b x 32j outputs (2 each) ----
        if (tid < 64) {
            float s0 = 0.f, s1 = 0.f;
            if (t > 0) {
                #pragma unroll
                for (int wv2 = 0; wv2 < 8; ++wv2) {
                    s0 += red[wv2][be][je];
                    s1 += red[wv2][be + 2][je];
                }
            }
            const float h0 = fast_tanh(xp0 + s0);
            const float h1 = fast_tanh(xp1 + s1);
            const size_t i0 = ((size_t)(b0 + be)     * S_SZ + t) * H_SZ + col0 + je;
            const size_t i1 = ((size_t)(b0 + be + 2) * S_SZ + t) * H_SZ + col0 + je;
            // publish H_t at the agent coherent point (cache-bypassing)
            __hip_atomic_store((float*)&HS[i0], h0, __ATOMIC_RELAXED,
                               __HIP_MEMORY_SCOPE_AGENT);
            __hip_atomic_store((float*)&HS[i1], h1, __ATOMIC_RELAXED,
                               __HIP_MEMORY_SCOPE_AGENT);
            if (t == S_SZ - 1) {
                Hlast[(size_t)(b0 + be)     * H_SZ + col0 + je] = h0;
                Hlast[(size_t)(b0 + be + 2) * H_SZ + col0 + je] = h1;
            }
            // drain THIS wave's stores (all 128 outputs come from wave 0),
            // then publish the step counter. No block barrier needed: the
            // other 7 waves are already polling/staging step t+1.
            asm volatile("s_waitcnt vmcnt(0)" ::: "memory");
            if (tid == 0) {
                __hip_atomic_store(mycnt, (unsigned int)(t + 1),
                                   __ATOMIC_RELAXED, __HIP_MEMORY_SCOPE_AGENT);
            }
        }
        // No end-of-step barrier: Hs rewrite (next staging) is safe because
        // every wave's MAC reads completed before barrier B; red rewrite is
        // safe because it happens after the NEXT barrier A, which wave 0 only
        // reaches after finishing this epilogue.
    }
}

extern "C" void kernel_launch(void* const* d_in, const int* in_sizes, int n_in,
                              void* d_out, int out_size, void* d_ws, size_t ws_size,
                              hipStream_t stream) {
    const float* X    = (const float*)d_in[0];  // [B,S,K]
    const float* W_xh = (const float*)d_in[1];  // [K,H]
    const float* W_hh = (const float*)d_in[2];  // [H,H]
    const float* b_h  = (const float*)d_in[3];  // [H]
    float* out = (float*)d_out;
    float* Hlast = out + (size_t)B_SZ * S_SZ * H_SZ;
    unsigned int* cnt = (unsigned int*)d_ws;    // [8][32] counters (1 KB)

    // zero sync counters (d_ws is re-poisoned before every launch)
    init_cnt<<<1, 256, 0, stream>>>(cnt, 8 * 32);

    // Phase 1: Xp = X @ W_xh + b into d_out's [B,S,H] region.
    dim3 gridA(H_SZ / BN, (B_SZ * S_SZ) / BM);
    proj_gemm<<<gridA, 256, 0, stream>>>(X, W_xh, b_h, out,
                                         B_SZ * S_SZ, H_SZ, K_SZ);

    // Phase 2: all 1024 recurrence steps in one persistent kernel.
    rnn_persist<<<256, 512, 0, stream>>>(out, W_hh, Hlast, cnt);
}

// Round 3
// 4247.861 us; speedup vs baseline: 1.3531x; 1.3531x over previous
//
#include <hip/hip_runtime.h>
#include <math.h>

// Elman RNN: out[b][t][j] = H_t, H_t = tanh(X_t @ W_xh + H_{t-1} @ W_hh + b)
// Phase 1: proj_gemm writes Xp = X@W_xh + b into d_out's [B,S,H] region.
// Phase 2: ONE persistent kernel runs all 1024 steps.
//
// R7 = exact revert to the R4 protocol (measured 4016 us persist; R5=4597,
// R6=5005 both regressed despite "better" micro-structure — two bundled
// protocol rewrites, two losses, so the R4 sync protocol is restored
// byte-for-byte) + two protocol-INDEPENDENT critical-path cuts:
//  (1) Xp prefetch at loop top: FETCH_SIZE ~= one full pass over Xp (128 MB)
//      => the epilogue's HS[idx] read was a cold HBM miss (~900 cy) sitting
//      after the reduce barrier every step. Prefetch issues it before the
//      poll; it completes under poll/stage/MAC. Safe in-place: each address
//      is prefetched strictly before its own overwrite; cross-block readers
//      use agent atomics (L1/L2 bypass).
//  (2) fast tanh (exp2 identity, ~10 VALU ops vs libm tanhf's long sequence;
//      error ~1e-6 << 3.9e-3 budget, absmax unchanged in R5/R6).
// R4 protocol (kept): per-(g,t) aggregated flag, 32 producer fetch_adds,
// tid0 poll + s_sleep(2) + syncthreads release, 4 barriers/step, 128-thread
// epilogue, conflict-free staging map (lane stride 8B).
// All cross-block H traffic uses agent-scope RELAXED atomics (complete at
// L3, coherent across XCDs). NO __threadfence (round-3 failure: full-L2
// writeback walks). W_hh strip asm-pinned in registers (round-3 bug:
// compiler re-loaded W every step).

#define B_SZ 32
#define S_SZ 1024
#define H_SZ 1024
#define K_SZ 1024

// ---------------- Phase 1: input projection GEMM (fp32) ----------------
#define BM 128
#define BN 128
#define BK 8

__global__ __launch_bounds__(256) void proj_gemm(
    const float* __restrict__ A,     // X   [M,K]
    const float* __restrict__ Bm,    // W_xh[K,N]
    const float* __restrict__ bias,  // [N]
    float* __restrict__ C,           // [M,N] (d_out Xp region)
    int M, int N, int K)
{
    __shared__ float As[BK][BM];   // transposed: As[k][m]
    __shared__ float Bs[BK][BN];

    const int tid  = threadIdx.x;
    const int row0 = blockIdx.y * BM;
    const int col0 = blockIdx.x * BN;
    const int tx = tid & 15;
    const int ty = tid >> 4;
    const int mBase = ty * 8;
    const int nBase = tx * 8;

    float acc[8][8];
    #pragma unroll
    for (int i = 0; i < 8; ++i)
        #pragma unroll
        for (int j = 0; j < 8; ++j) acc[i][j] = 0.f;

    for (int k0 = 0; k0 < K; k0 += BK) {
        {
            const int r  = tid >> 1;
            const int kq = (tid & 1) * 4;
            const float4 av = *(const float4*)(&A[(size_t)(row0 + r) * K + k0 + kq]);
            As[kq + 0][r] = av.x;
            As[kq + 1][r] = av.y;
            As[kq + 2][r] = av.z;
            As[kq + 3][r] = av.w;
            const int kr = tid >> 5;
            const int cq = (tid & 31) * 4;
            *(float4*)(&Bs[kr][cq]) =
                *(const float4*)(&Bm[(size_t)(k0 + kr) * N + col0 + cq]);
        }
        __syncthreads();

        #pragma unroll
        for (int kk = 0; kk < BK; ++kk) {
            float a[8], b[8];
            *(float4*)&a[0] = *(const float4*)&As[kk][mBase];
            *(float4*)&a[4] = *(const float4*)&As[kk][mBase + 4];
            *(float4*)&b[0] = *(const float4*)&Bs[kk][nBase];
            *(float4*)&b[4] = *(const float4*)&Bs[kk][nBase + 4];
            #pragma unroll
            for (int i = 0; i < 8; ++i)
                #pragma unroll
                for (int j = 0; j < 8; ++j)
                    acc[i][j] += a[i] * b[j];
        }
        __syncthreads();
    }

    #pragma unroll
    for (int i = 0; i < 8; ++i) {
        const int r = row0 + mBase + i;
        #pragma unroll
        for (int jq = 0; jq < 8; jq += 4) {
            const int c = col0 + nBase + jq;
            const float4 bv = *(const float4*)(&bias[c]);
            float4 o;
            o.x = acc[i][jq + 0] + bv.x;
            o.y = acc[i][jq + 1] + bv.y;
            o.z = acc[i][jq + 2] + bv.z;
            o.w = acc[i][jq + 3] + bv.w;
            *(float4*)(&C[(size_t)r * N + c]) = o;
        }
    }
}

// ---------------- init: zero the sync counters in d_ws ----------------
__global__ void init_cnt(unsigned int* __restrict__ cnt, int n) {
    int i = blockIdx.x * 256 + threadIdx.x;
    if (i < n) cnt[i] = 0u;
}

// fast tanh: tanh(x) = (e^{2x}-1)/(e^{2x}+1). Clamp keeps exp finite; output
// error ~1e-6 absolute — negligible vs the 3.9e-3 absmax budget.
__device__ __forceinline__ float fast_tanh(float x) {
    const float cx = fminf(fmaxf(x, -15.f), 15.f);
    const float e  = __expf(2.f * cx);
    return __fdividef(e - 1.f, e + 1.f);
}

// ---------------- Phase 2: persistent recurrence kernel ----------------
// 256 blocks x 512 threads, 1 block/CU.
// Block (g = blockIdx&7, c = blockIdx>>3): batches [4g,4g+4), cols [32c,32c+32).
// Thread (j = tid&31 -> col, seg = tid>>5 in [0,16) -> k range [64*seg,+64)).
// W strip in registers: w[64] = W_hh[64*seg + i][32c + j], asm-pinned.
// Per-step sync: cnt[g][t] arrival counters (32 producers per (g,t)).
// ALL cross-block H traffic uses agent-scope relaxed atomics (L3-coherent).
__global__ __launch_bounds__(512, 2) void rnn_persist(
    float* __restrict__ HS,        // d_out [B][S][H]; Xp in, H out (in place)
    const float* __restrict__ W,   // W_hh [K][H]
    float* __restrict__ Hlast,     // d_out + B*S*H
    unsigned int* __restrict__ cnt // [8][S_SZ]
    )
{
    const int g    = blockIdx.x & 7;
    const int c    = blockIdx.x >> 3;
    const int col0 = c * 32;
    const int b0   = g * 4;
    const int tid  = threadIdx.x;
    const int j    = tid & 31;
    const int seg  = tid >> 5;          // 0..15

    __shared__ __align__(16) float Hs[4][1024];     // H_{t-1} for 4 batches
    __shared__ float red[8][4][32];                 // per-wave partials

    // Load W strip into registers (once), then pin: the asm makes the values
    // opaque so the compiler cannot sink/rematerialize the loads into the
    // t-loop (round-3 bug: VGPR_Count=52 => W re-loaded every step).
    float w[64];
    {
        const float* wp = W + (size_t)(seg * 64) * H_SZ + col0 + j;
        #pragma unroll
        for (int i = 0; i < 64; ++i) w[i] = wp[(size_t)i * H_SZ];
        #pragma unroll
        for (int i = 0; i < 64; ++i) asm volatile("" : "+v"(w[i]));
    }

    unsigned int* flag = cnt + g * S_SZ;

    // epilogue map (tid < 128): b = tid>>5, jj = tid&31
    const int eb = tid >> 5;
    const int ej = tid & 31;

    for (int t = 0; t < S_SZ; ++t) {
        // ---- Xp prefetch (R7): issue the epilogue's HBM read at loop top,
        //      before the poll, so its ~900cy miss hides under poll/stage/MAC.
        float xp = 0.f;
        size_t eidx = 0;
        if (tid < 128) {
            eidx = ((size_t)(b0 + eb) * S_SZ + t) * H_SZ + col0 + ej;
            xp = HS[eidx];   // plain load; first & only pre-overwrite reader
        }

        if (t > 0) {
            // ---- wait for H_{t-1} of this batch group (relaxed poll) ----
            if (tid == 0) {
                while (__hip_atomic_load(flag + (t - 1), __ATOMIC_RELAXED,
                                         __HIP_MEMORY_SCOPE_AGENT) < 32u) {
                    __builtin_amdgcn_s_sleep(2);
                }
            }
            __syncthreads();

            // ---- stage H_{t-1}[b0..b0+3][:] into LDS (16 KB) via 8-byte
            //      agent atomic loads (bypass L1/L2, read L3-fresh) ----
            #pragma unroll
            for (int ch = 0; ch < 4; ++ch) {
                const int f8 = tid + ch * 512;        // [0,2048) qword slots
                const int b  = f8 >> 9;               // 512 qwords per batch
                const int qw = f8 & 511;
                const unsigned long long* src = (const unsigned long long*)
                    (&HS[((size_t)(b0 + b) * S_SZ + (t - 1)) * H_SZ]);
                const unsigned long long v8 = __hip_atomic_load(
                    &src[qw], __ATOMIC_RELAXED, __HIP_MEMORY_SCOPE_AGENT);
                *(unsigned long long*)(&Hs[b][qw * 2]) = v8;
            }
            __syncthreads();

            // ---- MAC: acc[b] = sum_{k in seg range} H[b][k] * W[k][j] ----
            float acc[4];
            #pragma unroll
            for (int b = 0; b < 4; ++b) {
                const float4* hb = (const float4*)(&Hs[b][seg * 64]);
                float a = 0.f;
                #pragma unroll
                for (int q = 0; q < 16; ++q) {
                    const float4 h = hb[q];   // broadcast across 32 j-lanes
                    a += h.x * w[4 * q + 0];
                    a += h.y * w[4 * q + 1];
                    a += h.z * w[4 * q + 2];
                    a += h.w * w[4 * q + 3];
                }
                acc[b] = a;
            }
            // combine the two k-halves within the wave (seg ^ 1)
            #pragma unroll
            for (int b = 0; b < 4; ++b) acc[b] += __shfl_xor(acc[b], 32);
            const int wv = tid >> 6;
            if ((tid & 63) < 32) {
                #pragma unroll
                for (int b = 0; b < 4; ++b) red[wv][b][j] = acc[b];
            }
            __syncthreads();
        }

        // ---- epilogue: first 128 threads own the 4b x 32j outputs ----
        if (tid < 128) {
            float s = 0.f;
            if (t > 0) {
                #pragma unroll
                for (int wv2 = 0; wv2 < 8; ++wv2) s += red[wv2][eb][ej];
            }
            const float v = fast_tanh(xp + s);
            // publish H_t at the agent coherent point (no fence needed)
            __hip_atomic_store(&HS[eidx], v, __ATOMIC_RELAXED,
                               __HIP_MEMORY_SCOPE_AGENT);
            if (t == S_SZ - 1)
                Hlast[(size_t)(b0 + eb) * H_SZ + col0 + ej] = v;
        }

        // __syncthreads: compiler emits s_waitcnt vmcnt(0) before s_barrier,
        // so all atomic H stores above are agent-visible before we arrive.
        __syncthreads();
        if (tid == 0) {
            __hip_atomic_fetch_add(flag + t, 1u, __ATOMIC_RELAXED,
                                   __HIP_MEMORY_SCOPE_AGENT);
        }
    }
}

extern "C" void kernel_launch(void* const* d_in, const int* in_sizes, int n_in,
                              void* d_out, int out_size, void* d_ws, size_t ws_size,
                              hipStream_t stream) {
    const float* X    = (const float*)d_in[0];  // [B,S,K]
    const float* W_xh = (const float*)d_in[1];  // [K,H]
    const float* W_hh = (const float*)d_in[2];  // [H,H]
    const float* b_h  = (const float*)d_in[3];  // [H]
    float* out = (float*)d_out;
    float* Hlast = out + (size_t)B_SZ * S_SZ * H_SZ;
    unsigned int* cnt = (unsigned int*)d_ws;    // [8][S_SZ] counters

    // zero sync counters (d_ws is re-poisoned before every launch)
    init_cnt<<<(8 * S_SZ + 255) / 256, 256, 0, stream>>>(cnt, 8 * S_SZ);

    // Phase 1: Xp = X @ W_xh + b into d_out's [B,S,H] region.
    dim3 gridA(H_SZ / BN, (B_SZ * S_SZ) / BM);
    proj_gemm<<<gridA, 256, 0, stream>>>(X, W_xh, b_h, out,
                                         B_SZ * S_SZ, H_SZ, K_SZ);

    // Phase 2: all 1024 recurrence steps in one persistent kernel.
    rnn_persist<<<256, 512, 0, stream>>>(out, W_hh, Hlast, cnt);
}